// Round 3
// baseline (488.598 us; speedup 1.0000x reference)
//
#include <hip/hip_runtime.h>
#include <math.h>

#define N_NODES 50000
#define N_EDGES 800000
#define N_GRAPHS 512
#define SLOPE 0.2f
#define CAP 48   // bucket capacity; degrees ~Binomial(800k,1/50k)~Poisson(16), P(deg>48)~1e-11
static constexpr float EPS_BN = 1e-5f;

typedef float v2f __attribute__((ext_vector_type(2)));

// ---------------- fused bucket-scatter (4 indep atomic chains/thread) + layer-0 ----
// Record = {float_bits(src*64), e0, e1, e2} : 16B, ea embedded, src pre-scaled to
// element offset so gat can use 32-bit saddr addressing (1 VALU per gather address).
// Scatter is latency-bound (VALU 2.8%, HBM 19%): EPT=4 pipelines 4 independent
// dst->atomic->store chains per thread.

__global__ __launch_bounds__(256) void scatter_t11_kernel(
    const int* __restrict__ src, const int* __restrict__ dst,
    const float* __restrict__ ea,
    int* __restrict__ cnt, float4* __restrict__ rec,
    const float* __restrict__ x,
    const float* __restrict__ Wl0, const float* __restrict__ bl0,
    const float* __restrict__ Wr0, const float* __restrict__ br0,
    float* __restrict__ xl, float* __restrict__ xr) {
    int t = threadIdx.x;
    int base = blockIdx.x * 1024 + t;
    int d[4], s[4], p[4];
    float a0[4], a1[4], a2[4];
    bool v[4];
#pragma unroll
    for (int i = 0; i < 4; i++) {
        int e = base + i * 256;
        v[i] = e < N_EDGES;
        int ec = v[i] ? e : 0;
        d[i] = dst[ec];
        s[i] = src[ec];
        a0[i] = ea[ec * 3 + 0];
        a1[i] = ea[ec * 3 + 1];
        a2[i] = ea[ec * 3 + 2];
    }
#pragma unroll
    for (int i = 0; i < 4; i++)
        p[i] = v[i] ? atomicAdd(&cnt[d[i]], 1) : CAP;
#pragma unroll
    for (int i = 0; i < 4; i++)
        if (v[i] && p[i] < CAP)
            rec[(size_t)d[i] * CAP + p[i]] =
                make_float4(__int_as_float(s[i] * 64), a0[i], a1[i], a2[i]);

    // layer-0 transform: grid-stride waves, 4 nodes/block-pass
    int w = t >> 6;
    int k = t & 63;
    v2f wlr[9];
#pragma unroll
    for (int j = 0; j < 9; j++) wlr[j] = (v2f){Wl0[j * 64 + k], Wr0[j * 64 + k]};
    v2f bias = {bl0[k], br0[k]};
    const int NW = gridDim.x * 4;
    for (int n = blockIdx.x * 4 + w; n < N_NODES; n += NW) {
        int un = __builtin_amdgcn_readfirstlane(n);
        const float* __restrict__ hrow = x + (size_t)un * 9;
        float hb[9];
#pragma unroll
        for (int j = 0; j < 9; j++) hb[j] = hrow[j];
        v2f acc = bias;
#pragma unroll
        for (int j = 0; j < 9; j++)
            acc = __builtin_elementwise_fma((v2f){hb[j], hb[j]}, wlr[j], acc);
        xl[(size_t)un * 64 + k] = acc.x;
        xr[(size_t)un * 64 + k] = acc.y;
    }
}

// ---------------- main transform (K=64): LDS-tiled GEMM, conflict-free LDS reads ----

__global__ __launch_bounds__(256) void transform7_kernel(
    const float* __restrict__ h,
    const float* __restrict__ Wl, const float* __restrict__ bl,
    const float* __restrict__ Wr, const float* __restrict__ br,
    float* __restrict__ xl, float* __restrict__ xr) {
    __shared__ __attribute__((aligned(16))) float sAt[64][68];
    __shared__ __attribute__((aligned(16))) float sB[64][128];
    int t = threadIdx.x;
    int n0 = blockIdx.x * 64;

#pragma unroll
    for (int i = 0; i < 4; i++) {
        int idx = i * 256 + t;
        int row = idx >> 4;
        int fc  = idx & 15;
        int n = n0 + row;
        float4 v = (n < N_NODES) ? *((const float4*)(h + (size_t)n * 64 + fc * 4))
                                 : make_float4(0.f, 0.f, 0.f, 0.f);
        sAt[fc * 4 + 0][row] = v.x;
        sAt[fc * 4 + 1][row] = v.y;
        sAt[fc * 4 + 2][row] = v.z;
        sAt[fc * 4 + 3][row] = v.w;
    }
#pragma unroll
    for (int i = 0; i < 8; i++) {
        int idx = i * 256 + t;
        int j  = idx >> 5;
        int fc = idx & 31;
        int c  = fc * 4;
        float4 v = (c < 64) ? *((const float4*)(Wl + j * 64 + c))
                            : *((const float4*)(Wr + j * 64 + (c - 64)));
        *((float4*)&sB[j][c]) = v;
    }
    __syncthreads();

    int tx = t & 15, ty = t >> 4;
    int c0 = tx * 4;
    float4 bls = *((const float4*)(bl + c0));
    float4 brs = *((const float4*)(br + c0));
    v2f acc[4][4];
#pragma unroll
    for (int r = 0; r < 4; r++) {
        acc[r][0] = (v2f){bls.x, bls.y};
        acc[r][1] = (v2f){bls.z, bls.w};
        acc[r][2] = (v2f){brs.x, brs.y};
        acc[r][3] = (v2f){brs.z, brs.w};
    }

#pragma unroll 4
    for (int j = 0; j < 64; j++) {
        // 16B-aligned b128 read: 4 distinct addresses/wave (broadcast within 16 lanes)
        float4 av = *((const float4*)&sAt[j][ty * 4]);
        float4 bq0 = *((const float4*)&sB[j][c0]);        // Wl cols c0..c0+3
        float4 bq1 = *((const float4*)&sB[j][64 + c0]);   // Wr cols c0..c0+3
        v2f b0 = {bq0.x, bq0.y}, b1 = {bq0.z, bq0.w};
        v2f b2 = {bq1.x, bq1.y}, b3 = {bq1.z, bq1.w};
        v2f a0v = {av.x, av.x}, a1v = {av.y, av.y}, a2v = {av.z, av.z}, a3v = {av.w, av.w};
        acc[0][0] = __builtin_elementwise_fma(a0v, b0, acc[0][0]);
        acc[0][1] = __builtin_elementwise_fma(a0v, b1, acc[0][1]);
        acc[0][2] = __builtin_elementwise_fma(a0v, b2, acc[0][2]);
        acc[0][3] = __builtin_elementwise_fma(a0v, b3, acc[0][3]);
        acc[1][0] = __builtin_elementwise_fma(a1v, b0, acc[1][0]);
        acc[1][1] = __builtin_elementwise_fma(a1v, b1, acc[1][1]);
        acc[1][2] = __builtin_elementwise_fma(a1v, b2, acc[1][2]);
        acc[1][3] = __builtin_elementwise_fma(a1v, b3, acc[1][3]);
        acc[2][0] = __builtin_elementwise_fma(a2v, b0, acc[2][0]);
        acc[2][1] = __builtin_elementwise_fma(a2v, b1, acc[2][1]);
        acc[2][2] = __builtin_elementwise_fma(a2v, b2, acc[2][2]);
        acc[2][3] = __builtin_elementwise_fma(a2v, b3, acc[2][3]);
        acc[3][0] = __builtin_elementwise_fma(a3v, b0, acc[3][0]);
        acc[3][1] = __builtin_elementwise_fma(a3v, b1, acc[3][1]);
        acc[3][2] = __builtin_elementwise_fma(a3v, b2, acc[3][2]);
        acc[3][3] = __builtin_elementwise_fma(a3v, b3, acc[3][3]);
    }

#pragma unroll
    for (int r = 0; r < 4; r++) {
        int n = n0 + ty * 4 + r;
        if (n < N_NODES) {
            *((float4*)(xl + (size_t)n * 64 + c0)) =
                make_float4(acc[r][0].x, acc[r][0].y, acc[r][1].x, acc[r][1].y);
            *((float4*)(xr + (size_t)n * 64 + c0)) =
                make_float4(acc[r][2].x, acc[r][2].y, acc[r][3].x, acc[r][3].y);
        }
    }
}

// ---------------- fused GATv2 layer: 8-edge pipeline + next-node cnt/xr prefetch ----

#define EDGE_T(rX, xXa, xXb, accX)                                        \
    {                                                                     \
        v2f tXa = xXa + xra, tXb = xXb + xrb;                             \
        tXa = __builtin_elementwise_fma((v2f){rX.y, rX.y}, we0a, tXa);    \
        tXb = __builtin_elementwise_fma((v2f){rX.y, rX.y}, we0b, tXb);    \
        tXa = __builtin_elementwise_fma((v2f){rX.z, rX.z}, we1a, tXa);    \
        tXb = __builtin_elementwise_fma((v2f){rX.z, rX.z}, we1b, tXb);    \
        tXa = __builtin_elementwise_fma((v2f){rX.w, rX.w}, we2a, tXa);    \
        tXb = __builtin_elementwise_fma((v2f){rX.w, rX.w}, we2b, tXb);    \
        tXa = __builtin_elementwise_max(tXa, tXa * SLOPE);                \
        tXb = __builtin_elementwise_max(tXb, tXb * SLOPE);                \
        v2f dX = ata * tXa;                                               \
        dX = __builtin_elementwise_fma(atb, tXb, dX);                     \
        accX = dX.x + dX.y;                                               \
    }

__global__ __launch_bounds__(256) void gat_fused10_kernel(
    const float* __restrict__ xl, const float* __restrict__ xr,
    const float4* __restrict__ recP, const int* __restrict__ cnt,
    const float* __restrict__ We, const float* __restrict__ att,
    const float* __restrict__ bo,
    const float* __restrict__ bn_g, const float* __restrict__ bn_b,
    const float* __restrict__ bn_m, const float* __restrict__ bn_v,
    float* __restrict__ hout) {
    int t = threadIdx.x;
    int w = t >> 6;
    int lane = t & 63;
    int q = lane >> 4;
    int r = lane & 15;
    int k4 = r * 4;

    // layer-invariant constants (hoisted out of the node loop)
    float4 we0 = *(const float4*)(We + 0 * 64 + k4);
    float4 we1 = *(const float4*)(We + 64 + k4);
    float4 we2 = *(const float4*)(We + 128 + k4);
    float4 at4 = *(const float4*)(att + k4);
    v2f we0a = {we0.x, we0.y}, we0b = {we0.z, we0.w};
    v2f we1a = {we1.x, we1.y}, we1b = {we1.z, we1.w};
    v2f we2a = {we2.x, we2.y}, we2b = {we2.z, we2.w};
    v2f ata  = {at4.x, at4.y}, atb  = {at4.z, at4.w};
    // fold bias+BN into res = max(o*zi*S + C, 0)
    float4 bo4 = *(const float4*)(bo + k4);
    float4 g4  = *(const float4*)(bn_g + k4);
    float4 b4  = *(const float4*)(bn_b + k4);
    float4 m4  = *(const float4*)(bn_m + k4);
    float4 v4  = *(const float4*)(bn_v + k4);
    float4 S, C;
    S.x = g4.x / sqrtf(v4.x + EPS_BN);  C.x = (bo4.x - m4.x) * S.x + b4.x;
    S.y = g4.y / sqrtf(v4.y + EPS_BN);  C.y = (bo4.y - m4.y) * S.y + b4.y;
    S.z = g4.z / sqrtf(v4.z + EPS_BN);  C.z = (bo4.z - m4.z) * S.z + b4.z;
    S.w = g4.w / sqrtf(v4.w + EPS_BN);  C.w = (bo4.w - m4.w) * S.w + b4.w;

    const int NW = gridDim.x * 4;
    int n0 = blockIdx.x * 4 + w;
    if (n0 >= N_NODES) return;
    int nU = __builtin_amdgcn_readfirstlane(n0);
    int cn = cnt[nU];
    float4 xq = *(const float4*)(xr + (size_t)nU * 64 + k4);

    while (true) {
        int n = nU;
        v2f xra = {xq.x, xq.y}, xrb = {xq.z, xq.w};
        int beg = n * CAP;
        int end = beg + min(cn, CAP);

        // prefetch next node's cnt (SGPR) and xr row — overlaps the edge loop
        int n1 = n0 + NW;
        bool hasNext = n1 < N_NODES;
        int nU1 = __builtin_amdgcn_readfirstlane(hasNext ? n1 : n0);
        int cn1 = cnt[nU1];
        float4 xq1 = *(const float4*)(xr + (size_t)nU1 * 64 + k4);

        v2f oAa = {0.f, 0.f}, oAb = {0.f, 0.f};
        v2f oBa = {0.f, 0.f}, oBb = {0.f, 0.f};
        float zA = 0.f, zB = 0.f;

        // software pipeline: recs for iteration i+1 load while iteration i computes
        int c = beg;
        int pA = c + q;     bool vA = pA < end;
        int pB = c + 4 + q; bool vB = pB < end;
        float4 rA = recP[vA ? pA : beg];
        float4 rB = recP[vB ? pB : beg];

        while (c < end) {
            // gathers for current recs (offsets ready in registers)
            unsigned offA = (unsigned)__float_as_int(rA.x) + k4;
            unsigned offB = (unsigned)__float_as_int(rB.x) + k4;
            float4 xA = *(const float4*)(xl + offA);
            float4 xB = *(const float4*)(xl + offB);

            // prefetch next iteration's recs (overlaps with gather latency + compute)
            int c2 = c + 8;
            int pA2 = c2 + q;     bool vA2 = pA2 < end;
            int pB2 = c2 + 4 + q; bool vB2 = pB2 < end;
            float4 rA2 = recP[vA2 ? pA2 : beg];
            float4 rB2 = recP[vB2 ? pB2 : beg];

            v2f xAa = {xA.x, xA.y}, xAb = {xA.z, xA.w};
            v2f xBa = {xB.x, xB.y}, xBb = {xB.z, xB.w};

            float accA, accB;
            EDGE_T(rA, xAa, xAb, accA);
            EDGE_T(rB, xBa, xBb, accB);

            accA += __shfl_xor(accA, 1, 64);  accB += __shfl_xor(accB, 1, 64);
            accA += __shfl_xor(accA, 2, 64);  accB += __shfl_xor(accB, 2, 64);
            accA += __shfl_xor(accA, 4, 64);  accB += __shfl_xor(accB, 4, 64);
            accA += __shfl_xor(accA, 8, 64);  accB += __shfl_xor(accB, 8, 64);

            float peA = vA ? __expf(accA) : 0.f;
            float peB = vB ? __expf(accB) : 0.f;
            v2f pA2v = {peA, peA}, pB2v = {peB, peB};
            oAa = __builtin_elementwise_fma(pA2v, xAa, oAa);
            oAb = __builtin_elementwise_fma(pA2v, xAb, oAb);
            oBa = __builtin_elementwise_fma(pB2v, xBa, oBa);
            oBb = __builtin_elementwise_fma(pB2v, xBb, oBb);
            zA += peA; zB += peB;

            rA = rA2; rB = rB2; vA = vA2; vB = vB2; c = c2;
        }

        v2f oa = oAa + oBa, ob = oAb + oBb;
        float z = zA + zB;
        float4 o = make_float4(oa.x, oa.y, ob.x, ob.y);
        o.x += __shfl_xor(o.x, 16, 64); o.x += __shfl_xor(o.x, 32, 64);
        o.y += __shfl_xor(o.y, 16, 64); o.y += __shfl_xor(o.y, 32, 64);
        o.z += __shfl_xor(o.z, 16, 64); o.z += __shfl_xor(o.z, 32, 64);
        o.w += __shfl_xor(o.w, 16, 64); o.w += __shfl_xor(o.w, 32, 64);
        z += __shfl_xor(z, 16, 64); z += __shfl_xor(z, 32, 64);

        if (q == 0) {
            float zi = 1.0f / fmaxf(z, 1e-16f);
            float4 res;
            res.x = fmaxf(fmaf(o.x * zi, S.x, C.x), 0.f);
            res.y = fmaxf(fmaf(o.y * zi, S.y, C.y), 0.f);
            res.z = fmaxf(fmaf(o.z * zi, S.z, C.z), 0.f);
            res.w = fmaxf(fmaf(o.w * zi, S.w, C.w), 0.f);
            *(float4*)(hout + (size_t)n * 64 + k4) = res;
        }

        if (!hasNext) break;
        n0 = n1; nU = nU1; cn = cn1; xq = xq1;
    }
}

// ---------------- readout: 4 waves/block, LDS cross-wave reduce ----------------

__global__ __launch_bounds__(256) void pool_all2_kernel(
    const float* __restrict__ h, const int* __restrict__ batch,
    const float* __restrict__ Wjk, const float* __restrict__ bjk,
    const float* __restrict__ Whead, const float* __restrict__ bhead,
    float* __restrict__ out) {
    __shared__ float red[4][64];
    int g = blockIdx.x;
    int t = threadIdx.x;
    int k = t & 63;
    int w = t >> 6;
    int lo = 0, hi = N_NODES;
    while (lo < hi) { int mid = (lo + hi) >> 1; if (batch[mid] < g) lo = mid + 1; else hi = mid; }
    int s = lo;
    hi = N_NODES;
    while (lo < hi) { int mid = (lo + hi) >> 1; if (batch[mid] < g + 1) lo = mid + 1; else hi = mid; }
    int e = lo;

    float acc = 0.f;
    for (int n = s + w; n < e; n += 4) acc += h[(size_t)n * 64 + k];
    red[w][k] = acc;
    __syncthreads();

    if (w == 0) {
        acc = (red[0][k] + red[1][k]) + (red[2][k] + red[3][k]);
        float wc = 0.f;
        for (int j = 0; j < 64; j++) wc = fmaf(Wjk[k * 64 + j], Whead[j], wc);
        float bc = bjk[k] * Whead[k];
        for (int off = 32; off > 0; off >>= 1) bc += __shfl_xor(bc, off, 64);
        float cntf = (float)(e - s);
        acc /= fmaxf(cntf, 1.0f);
        float v = acc * wc;
        for (int off = 32; off > 0; off >>= 1) v += __shfl_xor(v, off, 64);
        if (k == 0) out[g] = v + bc + bhead[0];
    }
}

// ---------------- launch ----------------

extern "C" void kernel_launch(void* const* d_in, const int* in_sizes, int n_in,
                              void* d_out, int out_size, void* d_ws, size_t ws_size,
                              hipStream_t stream) {
    const float* x     = (const float*)d_in[0];
    const float* ea    = (const float*)d_in[1];
    const float* Wl0   = (const float*)d_in[2];
    const float* Wr0   = (const float*)d_in[3];
    const float* bl0   = (const float*)d_in[4];
    const float* br0   = (const float*)d_in[5];
    const float* We0   = (const float*)d_in[6];
    const float* att0  = (const float*)d_in[7];
    const float* bo0   = (const float*)d_in[8];
    const float* Wl    = (const float*)d_in[9];
    const float* Wr    = (const float*)d_in[10];
    const float* bl    = (const float*)d_in[11];
    const float* br    = (const float*)d_in[12];
    const float* We    = (const float*)d_in[13];
    const float* att   = (const float*)d_in[14];
    const float* bo    = (const float*)d_in[15];
    const float* bn_g  = (const float*)d_in[16];
    const float* bn_b  = (const float*)d_in[17];
    const float* bn_m  = (const float*)d_in[18];
    const float* bn_v  = (const float*)d_in[19];
    const float* Wjk   = (const float*)d_in[20];
    const float* bjk   = (const float*)d_in[21];
    const float* Whead = (const float*)d_in[22];
    const float* bhead = (const float*)d_in[23];
    const int* edge_index = (const int*)d_in[24];
    const int* batch      = (const int*)d_in[25];

    const int* srcIdx = edge_index;            // edge_index[0]
    const int* dstIdx = edge_index + N_EDGES;  // edge_index[1]

    char* ws = (char*)d_ws;
    size_t off = 0;
    auto alloc = [&](size_t bytes) -> void* {
        void* p = ws + off;
        off += (bytes + 255) & ~(size_t)255;
        return p;
    };
    float* hA      = (float*)alloc((size_t)N_NODES * 64 * 4);
    float* hB      = (float*)alloc((size_t)N_NODES * 64 * 4);
    float* xlb     = (float*)alloc((size_t)N_NODES * 64 * 4);
    float* xrb     = (float*)alloc((size_t)N_NODES * 64 * 4);
    int*   cnt     = (int*)alloc((size_t)N_NODES * 4);
    float4* recP   = (float4*)alloc((size_t)N_NODES * CAP * 16);  // 38.4 MB

    // ---- fused bucket build (4 edges/thread) + layer-0 transform ----
    hipMemsetAsync(cnt, 0, (size_t)N_NODES * 4, stream);
    const int NSB = (N_EDGES + 1023) / 1024;   // 782
    scatter_t11_kernel<<<NSB, 256, 0, stream>>>(
        srcIdx, dstIdx, ea, cnt, recP, x, Wl0, bl0, Wr0, br0, xlb, xrb);

    const int GB  = 2048;                      // gat grid: grid-stride, ~6 nodes/wave
    const int NBG = (N_NODES + 63) / 64;       // 782 (GEMM transform grid)

    // ---- layer 0 GAT ----
    gat_fused10_kernel<<<GB, 256, 0, stream>>>(xlb, xrb, recP, cnt,
                                               We0, att0, bo0,
                                               bn_g, bn_b, bn_m, bn_v, hA);

    // ---- layers 1..4 ----
    float* hcur = hA;
    float* hnext = hB;
    for (int i = 0; i < 4; i++) {
        transform7_kernel<<<NBG, 256, 0, stream>>>(hcur,
            Wl + (size_t)i * 64 * 64, bl + (size_t)i * 64,
            Wr + (size_t)i * 64 * 64, br + (size_t)i * 64,
            xlb, xrb);
        gat_fused10_kernel<<<GB, 256, 0, stream>>>(xlb, xrb, recP, cnt,
            We + (size_t)i * 3 * 64, att + (size_t)i * 64,
            bo + (size_t)i * 64,
            bn_g + (size_t)(i + 1) * 64, bn_b + (size_t)(i + 1) * 64,
            bn_m + (size_t)(i + 1) * 64, bn_v + (size_t)(i + 1) * 64,
            hnext);
        float* tp = hcur; hcur = hnext; hnext = tp;
    }

    // ---- readout ----
    pool_all2_kernel<<<N_GRAPHS, 256, 0, stream>>>(hcur, batch, Wjk, bjk, Whead, bhead,
                                                   (float*)d_out);
}

// Round 4
// 447.910 us; speedup vs baseline: 1.0908x; 1.0908x over previous
//
#include <hip/hip_runtime.h>
#include <math.h>

#define N_NODES 50000
#define N_EDGES 800000
#define N_GRAPHS 512
#define SLOPE 0.2f
#define CAP 48   // bucket capacity; degrees ~Binomial(800k,1/50k)~Poisson(16), P(deg>48)~1e-11
static constexpr float EPS_BN = 1e-5f;

typedef float v2f __attribute__((ext_vector_type(2)));

// ---------------- fused bucket-scatter + layer-0 transform (known-good t9) ----------
// Record = {float_bits(src*64), e0, e1, e2} : 16B, ea embedded, src pre-scaled to
// element offset so gat can use 32-bit saddr addressing (1 VALU per gather address).
// NOTE (R3): EPT=4 variant regressed (occupancy 64%->28%; 200k threads < machine
// capacity). This kernel is TLP-bound: keep 1 edge/thread, 800k threads.

__global__ __launch_bounds__(256) void scatter_t9_kernel(
    const int* __restrict__ src, const int* __restrict__ dst,
    const float* __restrict__ ea,
    int* __restrict__ cnt, float4* __restrict__ rec,
    const float* __restrict__ x,
    const float* __restrict__ Wl0, const float* __restrict__ bl0,
    const float* __restrict__ Wr0, const float* __restrict__ br0,
    float* __restrict__ xl, float* __restrict__ xr) {
    int t = threadIdx.x;
    int e = blockIdx.x * 256 + t;
    if (e < N_EDGES) {
        int d = dst[e];
        int pos = atomicAdd(&cnt[d], 1);
        if (pos < CAP)
            rec[(size_t)d * CAP + pos] = make_float4(__int_as_float(src[e] * 64),
                                                     ea[e * 3 + 0], ea[e * 3 + 1], ea[e * 3 + 2]);
    }

    // layer-0 transform: grid-stride waves, 4 nodes/block-pass
    int w = t >> 6;
    int k = t & 63;
    v2f wlr[9];
#pragma unroll
    for (int j = 0; j < 9; j++) wlr[j] = (v2f){Wl0[j * 64 + k], Wr0[j * 64 + k]};
    v2f bias = {bl0[k], br0[k]};
    const int NW = gridDim.x * 4;
    for (int n = blockIdx.x * 4 + w; n < N_NODES; n += NW) {
        int un = __builtin_amdgcn_readfirstlane(n);
        const float* __restrict__ hrow = x + (size_t)un * 9;
        float hb[9];
#pragma unroll
        for (int j = 0; j < 9; j++) hb[j] = hrow[j];
        v2f acc = bias;
#pragma unroll
        for (int j = 0; j < 9; j++)
            acc = __builtin_elementwise_fma((v2f){hb[j], hb[j]}, wlr[j], acc);
        xl[(size_t)un * 64 + k] = acc.x;
        xr[(size_t)un * 64 + k] = acc.y;
    }
}

// ---------------- main transform (K=64): LDS-tiled GEMM (round-2 known-good) ------

__global__ __launch_bounds__(256) void transform6_kernel(
    const float* __restrict__ h,
    const float* __restrict__ Wl, const float* __restrict__ bl,
    const float* __restrict__ Wr, const float* __restrict__ br,
    float* __restrict__ xl, float* __restrict__ xr) {
    __shared__ float sAt[64][68];
    __shared__ float sB[64][128];
    int t = threadIdx.x;
    int n0 = blockIdx.x * 64;

#pragma unroll
    for (int i = 0; i < 4; i++) {
        int idx = i * 256 + t;
        int row = idx >> 4;
        int fc  = idx & 15;
        int n = n0 + row;
        float4 v = (n < N_NODES) ? *((const float4*)(h + (size_t)n * 64 + fc * 4))
                                 : make_float4(0.f, 0.f, 0.f, 0.f);
        sAt[fc * 4 + 0][row] = v.x;
        sAt[fc * 4 + 1][row] = v.y;
        sAt[fc * 4 + 2][row] = v.z;
        sAt[fc * 4 + 3][row] = v.w;
    }
#pragma unroll
    for (int i = 0; i < 8; i++) {
        int idx = i * 256 + t;
        int j  = idx >> 5;
        int fc = idx & 31;
        int c  = fc * 4;
        float4 v = (c < 64) ? *((const float4*)(Wl + j * 64 + c))
                            : *((const float4*)(Wr + j * 64 + (c - 64)));
        *((float4*)&sB[j][c]) = v;
    }
    __syncthreads();

    int tx = t & 15, ty = t >> 4;
    int c0 = tx * 4;
    float4 bls = *((const float4*)(bl + c0));
    float4 brs = *((const float4*)(br + c0));
    v2f acc[4][4];
#pragma unroll
    for (int r = 0; r < 4; r++) {
        acc[r][0] = (v2f){bls.x, bls.y};
        acc[r][1] = (v2f){bls.z, bls.w};
        acc[r][2] = (v2f){brs.x, brs.y};
        acc[r][3] = (v2f){brs.z, brs.w};
    }

#pragma unroll 4
    for (int j = 0; j < 64; j++) {
        float a0 = sAt[j][ty * 4 + 0];
        float a1 = sAt[j][ty * 4 + 1];
        float a2 = sAt[j][ty * 4 + 2];
        float a3 = sAt[j][ty * 4 + 3];
        float4 bq0 = *((const float4*)&sB[j][c0]);        // Wl cols c0..c0+3
        float4 bq1 = *((const float4*)&sB[j][64 + c0]);   // Wr cols c0..c0+3
        v2f b0 = {bq0.x, bq0.y}, b1 = {bq0.z, bq0.w};
        v2f b2 = {bq1.x, bq1.y}, b3 = {bq1.z, bq1.w};
        v2f a0v = {a0, a0}, a1v = {a1, a1}, a2v = {a2, a2}, a3v = {a3, a3};
        acc[0][0] = __builtin_elementwise_fma(a0v, b0, acc[0][0]);
        acc[0][1] = __builtin_elementwise_fma(a0v, b1, acc[0][1]);
        acc[0][2] = __builtin_elementwise_fma(a0v, b2, acc[0][2]);
        acc[0][3] = __builtin_elementwise_fma(a0v, b3, acc[0][3]);
        acc[1][0] = __builtin_elementwise_fma(a1v, b0, acc[1][0]);
        acc[1][1] = __builtin_elementwise_fma(a1v, b1, acc[1][1]);
        acc[1][2] = __builtin_elementwise_fma(a1v, b2, acc[1][2]);
        acc[1][3] = __builtin_elementwise_fma(a1v, b3, acc[1][3]);
        acc[2][0] = __builtin_elementwise_fma(a2v, b0, acc[2][0]);
        acc[2][1] = __builtin_elementwise_fma(a2v, b1, acc[2][1]);
        acc[2][2] = __builtin_elementwise_fma(a2v, b2, acc[2][2]);
        acc[2][3] = __builtin_elementwise_fma(a2v, b3, acc[2][3]);
        acc[3][0] = __builtin_elementwise_fma(a3v, b0, acc[3][0]);
        acc[3][1] = __builtin_elementwise_fma(a3v, b1, acc[3][1]);
        acc[3][2] = __builtin_elementwise_fma(a3v, b2, acc[3][2]);
        acc[3][3] = __builtin_elementwise_fma(a3v, b3, acc[3][3]);
    }

#pragma unroll
    for (int r = 0; r < 4; r++) {
        int n = n0 + ty * 4 + r;
        if (n < N_NODES) {
            *((float4*)(xl + (size_t)n * 64 + c0)) =
                make_float4(acc[r][0].x, acc[r][0].y, acc[r][1].x, acc[r][1].y);
            *((float4*)(xr + (size_t)n * 64 + c0)) =
                make_float4(acc[r][2].x, acc[r][2].y, acc[r][3].x, acc[r][3].y);
        }
    }
}

// ---------------- fused GATv2 layer: 2-deep pipeline (rec AND gather hidden) ------
// Per iteration i: issue gathers[i+1] (recs arrived), issue recs[i+2], compute i.
// Counted vmcnt keeps younger loads in flight across the compute.

#define EDGE_T(rX, xXa, xXb, accX)                                        \
    {                                                                     \
        v2f tXa = xXa + xra, tXb = xXb + xrb;                             \
        tXa = __builtin_elementwise_fma((v2f){rX.y, rX.y}, we0a, tXa);    \
        tXb = __builtin_elementwise_fma((v2f){rX.y, rX.y}, we0b, tXb);    \
        tXa = __builtin_elementwise_fma((v2f){rX.z, rX.z}, we1a, tXa);    \
        tXb = __builtin_elementwise_fma((v2f){rX.z, rX.z}, we1b, tXb);    \
        tXa = __builtin_elementwise_fma((v2f){rX.w, rX.w}, we2a, tXa);    \
        tXb = __builtin_elementwise_fma((v2f){rX.w, rX.w}, we2b, tXb);    \
        tXa = __builtin_elementwise_max(tXa, tXa * SLOPE);                \
        tXb = __builtin_elementwise_max(tXb, tXb * SLOPE);                \
        v2f dX = ata * tXa;                                               \
        dX = __builtin_elementwise_fma(atb, tXb, dX);                     \
        accX = dX.x + dX.y;                                               \
    }

__global__ __launch_bounds__(256) void gat_fused11_kernel(
    const float* __restrict__ xl, const float* __restrict__ xr,
    const float4* __restrict__ recP, const int* __restrict__ cnt,
    const float* __restrict__ We, const float* __restrict__ att,
    const float* __restrict__ bo,
    const float* __restrict__ bn_g, const float* __restrict__ bn_b,
    const float* __restrict__ bn_m, const float* __restrict__ bn_v,
    float* __restrict__ hout) {
    int t = threadIdx.x;
    int w = t >> 6;
    int lane = t & 63;
    int q = lane >> 4;
    int r = lane & 15;
    int k4 = r * 4;

    // layer-invariant constants (hoisted out of the node loop)
    float4 we0 = *(const float4*)(We + 0 * 64 + k4);
    float4 we1 = *(const float4*)(We + 64 + k4);
    float4 we2 = *(const float4*)(We + 128 + k4);
    float4 at4 = *(const float4*)(att + k4);
    v2f we0a = {we0.x, we0.y}, we0b = {we0.z, we0.w};
    v2f we1a = {we1.x, we1.y}, we1b = {we1.z, we1.w};
    v2f we2a = {we2.x, we2.y}, we2b = {we2.z, we2.w};
    v2f ata  = {at4.x, at4.y}, atb  = {at4.z, at4.w};
    // fold bias+BN into res = max(o*zi*S + C, 0)
    float4 bo4 = *(const float4*)(bo + k4);
    float4 g4  = *(const float4*)(bn_g + k4);
    float4 b4  = *(const float4*)(bn_b + k4);
    float4 m4  = *(const float4*)(bn_m + k4);
    float4 v4  = *(const float4*)(bn_v + k4);
    float4 S, C;
    S.x = g4.x / sqrtf(v4.x + EPS_BN);  C.x = (bo4.x - m4.x) * S.x + b4.x;
    S.y = g4.y / sqrtf(v4.y + EPS_BN);  C.y = (bo4.y - m4.y) * S.y + b4.y;
    S.z = g4.z / sqrtf(v4.z + EPS_BN);  C.z = (bo4.z - m4.z) * S.z + b4.z;
    S.w = g4.w / sqrtf(v4.w + EPS_BN);  C.w = (bo4.w - m4.w) * S.w + b4.w;

    const int NW = gridDim.x * 4;
    for (int n0 = blockIdx.x * 4 + w; n0 < N_NODES; n0 += NW) {
        int n = __builtin_amdgcn_readfirstlane(n0);
        float4 xq = *(const float4*)(xr + (size_t)n * 64 + k4);
        v2f xra = {xq.x, xq.y}, xrb = {xq.z, xq.w};
        int beg = n * CAP;
        int end = beg + min(cnt[n], CAP);

        v2f oAa = {0.f, 0.f}, oAb = {0.f, 0.f};
        v2f oBa = {0.f, 0.f}, oBb = {0.f, 0.f};
        float zA = 0.f, zB = 0.f;

        // ---- prologue: recs[0], recs[1] in flight; gathers[0] issued ----
        int c = beg;
        int pA0 = c + q;      bool vA0 = pA0 < end;
        int pB0 = c + 4 + q;  bool vB0 = pB0 < end;
        float4 rA0 = recP[vA0 ? pA0 : beg];
        float4 rB0 = recP[vB0 ? pB0 : beg];
        int pA1 = c + 8 + q;  bool vA1 = pA1 < end;
        int pB1 = c + 12 + q; bool vB1 = pB1 < end;
        float4 rA1 = recP[vA1 ? pA1 : beg];
        float4 rB1 = recP[vB1 ? pB1 : beg];
        float4 xA0 = *(const float4*)(xl + ((unsigned)__float_as_int(rA0.x) + k4));
        float4 xB0 = *(const float4*)(xl + ((unsigned)__float_as_int(rB0.x) + k4));

        while (c < end) {
            // gathers for iteration i+1 (recs rA1/rB1 arriving)
            float4 xA1 = *(const float4*)(xl + ((unsigned)__float_as_int(rA1.x) + k4));
            float4 xB1 = *(const float4*)(xl + ((unsigned)__float_as_int(rB1.x) + k4));
            // rec loads for iteration i+2
            int c2 = c + 16;
            int pA2 = c2 + q;     bool vA2 = pA2 < end;
            int pB2 = c2 + 4 + q; bool vB2 = pB2 < end;
            float4 rA2 = recP[vA2 ? pA2 : beg];
            float4 rB2 = recP[vB2 ? pB2 : beg];

            // compute iteration i (waits only xA0/xB0; vmcnt(4) keeps the rest out)
            v2f xAa = {xA0.x, xA0.y}, xAb = {xA0.z, xA0.w};
            v2f xBa = {xB0.x, xB0.y}, xBb = {xB0.z, xB0.w};

            float accA, accB;
            EDGE_T(rA0, xAa, xAb, accA);
            EDGE_T(rB0, xBa, xBb, accB);

            accA += __shfl_xor(accA, 1, 64);  accB += __shfl_xor(accB, 1, 64);
            accA += __shfl_xor(accA, 2, 64);  accB += __shfl_xor(accB, 2, 64);
            accA += __shfl_xor(accA, 4, 64);  accB += __shfl_xor(accB, 4, 64);
            accA += __shfl_xor(accA, 8, 64);  accB += __shfl_xor(accB, 8, 64);

            float peA = vA0 ? __expf(accA) : 0.f;
            float peB = vB0 ? __expf(accB) : 0.f;
            v2f pAv = {peA, peA}, pBv = {peB, peB};
            oAa = __builtin_elementwise_fma(pAv, xAa, oAa);
            oAb = __builtin_elementwise_fma(pAv, xAb, oAb);
            oBa = __builtin_elementwise_fma(pBv, xBa, oBa);
            oBb = __builtin_elementwise_fma(pBv, xBb, oBb);
            zA += peA; zB += peB;

            // rotate pipeline
            rA0 = rA1; rB0 = rB1; vA0 = vA1; vB0 = vB1;
            rA1 = rA2; rB1 = rB2; vA1 = vA2; vB1 = vB2;
            xA0 = xA1; xB0 = xB1;
            c += 8;
        }

        v2f oa = oAa + oBa, ob = oAb + oBb;
        float z = zA + zB;
        float4 o = make_float4(oa.x, oa.y, ob.x, ob.y);
        o.x += __shfl_xor(o.x, 16, 64); o.x += __shfl_xor(o.x, 32, 64);
        o.y += __shfl_xor(o.y, 16, 64); o.y += __shfl_xor(o.y, 32, 64);
        o.z += __shfl_xor(o.z, 16, 64); o.z += __shfl_xor(o.z, 32, 64);
        o.w += __shfl_xor(o.w, 16, 64); o.w += __shfl_xor(o.w, 32, 64);
        z += __shfl_xor(z, 16, 64); z += __shfl_xor(z, 32, 64);

        if (q == 0) {
            float zi = 1.0f / fmaxf(z, 1e-16f);
            float4 res;
            res.x = fmaxf(fmaf(o.x * zi, S.x, C.x), 0.f);
            res.y = fmaxf(fmaf(o.y * zi, S.y, C.y), 0.f);
            res.z = fmaxf(fmaf(o.z * zi, S.z, C.z), 0.f);
            res.w = fmaxf(fmaf(o.w * zi, S.w, C.w), 0.f);
            *(float4*)(hout + (size_t)n * 64 + k4) = res;
        }
    }
}

// ---------------- readout: 4 waves/block, LDS cross-wave reduce ----------------

__global__ __launch_bounds__(256) void pool_all2_kernel(
    const float* __restrict__ h, const int* __restrict__ batch,
    const float* __restrict__ Wjk, const float* __restrict__ bjk,
    const float* __restrict__ Whead, const float* __restrict__ bhead,
    float* __restrict__ out) {
    __shared__ float red[4][64];
    int g = blockIdx.x;
    int t = threadIdx.x;
    int k = t & 63;
    int w = t >> 6;
    int lo = 0, hi = N_NODES;
    while (lo < hi) { int mid = (lo + hi) >> 1; if (batch[mid] < g) lo = mid + 1; else hi = mid; }
    int s = lo;
    hi = N_NODES;
    while (lo < hi) { int mid = (lo + hi) >> 1; if (batch[mid] < g + 1) lo = mid + 1; else hi = mid; }
    int e = lo;

    float acc = 0.f;
    for (int n = s + w; n < e; n += 4) acc += h[(size_t)n * 64 + k];
    red[w][k] = acc;
    __syncthreads();

    if (w == 0) {
        acc = (red[0][k] + red[1][k]) + (red[2][k] + red[3][k]);
        float wc = 0.f;
        for (int j = 0; j < 64; j++) wc = fmaf(Wjk[k * 64 + j], Whead[j], wc);
        float bc = bjk[k] * Whead[k];
        for (int off = 32; off > 0; off >>= 1) bc += __shfl_xor(bc, off, 64);
        float cntf = (float)(e - s);
        acc /= fmaxf(cntf, 1.0f);
        float v = acc * wc;
        for (int off = 32; off > 0; off >>= 1) v += __shfl_xor(v, off, 64);
        if (k == 0) out[g] = v + bc + bhead[0];
    }
}

// ---------------- launch ----------------

extern "C" void kernel_launch(void* const* d_in, const int* in_sizes, int n_in,
                              void* d_out, int out_size, void* d_ws, size_t ws_size,
                              hipStream_t stream) {
    const float* x     = (const float*)d_in[0];
    const float* ea    = (const float*)d_in[1];
    const float* Wl0   = (const float*)d_in[2];
    const float* Wr0   = (const float*)d_in[3];
    const float* bl0   = (const float*)d_in[4];
    const float* br0   = (const float*)d_in[5];
    const float* We0   = (const float*)d_in[6];
    const float* att0  = (const float*)d_in[7];
    const float* bo0   = (const float*)d_in[8];
    const float* Wl    = (const float*)d_in[9];
    const float* Wr    = (const float*)d_in[10];
    const float* bl    = (const float*)d_in[11];
    const float* br    = (const float*)d_in[12];
    const float* We    = (const float*)d_in[13];
    const float* att   = (const float*)d_in[14];
    const float* bo    = (const float*)d_in[15];
    const float* bn_g  = (const float*)d_in[16];
    const float* bn_b  = (const float*)d_in[17];
    const float* bn_m  = (const float*)d_in[18];
    const float* bn_v  = (const float*)d_in[19];
    const float* Wjk   = (const float*)d_in[20];
    const float* bjk   = (const float*)d_in[21];
    const float* Whead = (const float*)d_in[22];
    const float* bhead = (const float*)d_in[23];
    const int* edge_index = (const int*)d_in[24];
    const int* batch      = (const int*)d_in[25];

    const int* srcIdx = edge_index;            // edge_index[0]
    const int* dstIdx = edge_index + N_EDGES;  // edge_index[1]

    char* ws = (char*)d_ws;
    size_t off = 0;
    auto alloc = [&](size_t bytes) -> void* {
        void* p = ws + off;
        off += (bytes + 255) & ~(size_t)255;
        return p;
    };
    float* hA      = (float*)alloc((size_t)N_NODES * 64 * 4);
    float* hB      = (float*)alloc((size_t)N_NODES * 64 * 4);
    float* xlb     = (float*)alloc((size_t)N_NODES * 64 * 4);
    float* xrb     = (float*)alloc((size_t)N_NODES * 64 * 4);
    int*   cnt     = (int*)alloc((size_t)N_NODES * 4);
    float4* recP   = (float4*)alloc((size_t)N_NODES * CAP * 16);  // 38.4 MB

    // ---- fused bucket build + layer-0 transform ----
    hipMemsetAsync(cnt, 0, (size_t)N_NODES * 4, stream);
    scatter_t9_kernel<<<(N_EDGES + 255) / 256, 256, 0, stream>>>(
        srcIdx, dstIdx, ea, cnt, recP, x, Wl0, bl0, Wr0, br0, xlb, xrb);

    const int GB  = 2048;                      // gat grid: grid-stride, ~6 nodes/wave
    const int NBG = (N_NODES + 63) / 64;       // 782 (GEMM transform grid)

    // ---- layer 0 GAT ----
    gat_fused11_kernel<<<GB, 256, 0, stream>>>(xlb, xrb, recP, cnt,
                                               We0, att0, bo0,
                                               bn_g, bn_b, bn_m, bn_v, hA);

    // ---- layers 1..4 ----
    float* hcur = hA;
    float* hnext = hB;
    for (int i = 0; i < 4; i++) {
        transform6_kernel<<<NBG, 256, 0, stream>>>(hcur,
            Wl + (size_t)i * 64 * 64, bl + (size_t)i * 64,
            Wr + (size_t)i * 64 * 64, br + (size_t)i * 64,
            xlb, xrb);
        gat_fused11_kernel<<<GB, 256, 0, stream>>>(xlb, xrb, recP, cnt,
            We + (size_t)i * 3 * 64, att + (size_t)i * 64,
            bo + (size_t)i * 64,
            bn_g + (size_t)(i + 1) * 64, bn_b + (size_t)(i + 1) * 64,
            bn_m + (size_t)(i + 1) * 64, bn_v + (size_t)(i + 1) * 64,
            hnext);
        float* tp = hcur; hcur = hnext; hnext = tp;
    }

    // ---- readout ----
    pool_all2_kernel<<<N_GRAPHS, 256, 0, stream>>>(hcur, batch, Wjk, bjk, Whead, bhead,
                                                   (float*)d_out);
}